// Round 6
// baseline (121301.758 us; speedup 1.0000x reference)
//
#include <hip/hip_runtime.h>

#define T_STEPS 32768
#define THREADS 256
#define NLAUNCH 512   // WGs launched; 64 become workers, rest exit

typedef unsigned int uint32;
typedef unsigned long long ull;
typedef unsigned int u32x4 __attribute__((ext_vector_type(4)));

// ws layout (host-computed, depth D in {16,8,4}):
// [0, 2*D*4096)        : hrot = ull[2 lstm][D][512]; each ull = {lo: tag=t+1, hi: f32 h bits}
// [+0, +128)           : step counters: ctr[0] (lstm0) at +0, ctr[16] (lstm1) at +64
// [+128, +256)         : claim area (32 uints)

__device__ inline float fsig(float x) {
    return __builtin_amdgcn_rcpf(1.f + __expf(-x));
}
__device__ inline float ftanh(float x) {
    return 1.f - 2.f * __builtin_amdgcn_rcpf(1.f + __expf(2.f * x));
}

// L2-executing atomic reads (inline asm -> cannot be elided to cached loads;
// no sc1 -> executes at the XCD-local L2, the same cache producers write through to)
__device__ inline uint32 poll32(uint32* p) {
    uint32 old;
    asm volatile("global_atomic_add %0, %1, %2, off sc0\n\t"
                 "s_waitcnt vmcnt(0)"
                 : "=&v"(old) : "v"(p), "v"(0u) : "memory");
    return old;
}
__device__ inline ull rmw64(ull* p) {
    ull old;
    asm volatile("global_atomic_add_x2 %0, %1, %2, off sc0\n\t"
                 "s_waitcnt vmcnt(0)"
                 : "=&v"(old) : "v"(p), "v"(0ull) : "memory");
    return old;
}

// claim-phase primitives (agent scope; only used once at startup)
__device__ inline uint32 a_add(uint32* p, uint32 v) {
    return __hip_atomic_fetch_add(p, v, __ATOMIC_RELAXED, __HIP_MEMORY_SCOPE_AGENT);
}
__device__ inline uint32 a_ld(const uint32* p) {
    return __hip_atomic_load(p, __ATOMIC_RELAXED, __HIP_MEMORY_SCOPE_AGENT);
}
__device__ inline void a_st(uint32* p, uint32 v) {
    __hip_atomic_store(p, v, __ATOMIC_RELAXED, __HIP_MEMORY_SCOPE_AGENT);
}

__global__ __launch_bounds__(THREADS, 2)
void lstm_persistent(const float* __restrict__ sa,
                     const float* __restrict__ W_ih1, const float* __restrict__ W_hh1,
                     const float* __restrict__ b_ih1, const float* __restrict__ b_hh1,
                     const float* __restrict__ W_ih2, const float* __restrict__ W_hh2,
                     const float* __restrict__ b_ih2, const float* __restrict__ b_hh2,
                     const float* __restrict__ W_xyz, const float* __restrict__ W_zeta,
                     const float* __restrict__ W_uvw, const float* __restrict__ W_pqr,
                     float* __restrict__ out, ull* hrot, uint32* ctr,
                     uint32* claim, uint32 dmask)
{
    const int tid  = threadIdx.x;
    const int wave = tid >> 6;
    const int lane = tid & 63;

    __shared__ int s_lstm, s_w;

    // ---- XCD-local role claiming (thread 0); agent-scope, startup-only ----
    if (tid == 0) {
        uint32 xcc;
        asm volatile("s_getreg_b32 %0, hwreg(HW_REG_XCC_ID)" : "=s"(xcc));
        xcc &= 7;
        uint32* cnt     = claim;            // [0..7]
        uint32* rankcnt = claim + 8;
        uint32* grank   = claim + 16;       // [xcd*2 + g]

        int lstm = -1, w = 0;
        uint32 slot = a_add(&cnt[xcc], 1);
        if (slot < 64) {
            uint32 g = slot >> 5, role = slot & 31;
            uint32* gr = &grank[xcc * 2 + g];
            if (role == 31) {                 // completer: group is full
                uint32 rank = a_add(rankcnt, 1);
                uint32 val  = (rank < 2) ? (rank + 1) : 0xFEu;
                a_st(gr, val);
                if (val != 0xFEu) { lstm = (int)rank; w = 31; }
            } else {                          // spinner
                for (;;) {
                    uint32 v = a_ld(gr);
                    if (v != 0) {
                        if (v != 0xFEu) { lstm = (int)v - 1; w = (int)role; }
                        break;
                    }
                    if (a_ld(rankcnt) >= 2 && a_ld(&cnt[xcc]) < (g + 1) * 32)
                        break;                // group can never get a valid rank
                }
            }
        }
        s_lstm = lstm; s_w = w;
    }
    __syncthreads();
    const int lstm = s_lstm;
    const int w    = s_w;
    if (lstm < 0) return;

    const float* W_ih = lstm ? W_ih2 : W_ih1;
    const float* W_hh = lstm ? W_hh2 : W_hh1;
    const float* b_ih = lstm ? b_ih2 : b_ih1;
    const float* b_hh = lstm ? b_hh2 : b_hh1;
    const float* W_a  = lstm ? W_zeta : W_xyz;
    const float* W_b  = lstm ? W_pqr  : W_uvw;

    ull*    hb    = hrot + (size_t)lstm * (dmask + 1) * 512;  // D slots x 512
    uint32* myctr = ctr + lstm * 16;                          // own 64B line

    __shared__ __align__(16) float h_lds[512];
    __shared__ float part_lds[64 * 5];
    __shared__ float wih_lds[64 * 19];

    const int r    = lane;
    const int jloc = r & 15;
    const int grow = ((r >> 4) << 9) + (w << 4) + jloc;

    // W_hh slice: 32 float4 = 128 weights / thread, pinned into VGPRs
    float4 wreg[32];
    {
        const float4* wp4 = (const float4*)(W_hh + (size_t)grow * 512 + wave * 128);
        #pragma unroll
        for (int k = 0; k < 32; ++k) wreg[k] = wp4[k];
        #pragma unroll
        for (int k = 0; k < 32; ++k)
            asm volatile("" :: "v"(wreg[k].x), "v"(wreg[k].y),
                              "v"(wreg[k].z), "v"(wreg[k].w));
    }
    for (int idx = tid; idx < 64 * 19; idx += THREADS) {
        int rr = idx / 19, kk = idx - rr * 19;
        int gr2 = ((rr >> 4) << 9) + (w << 4) + (rr & 15);
        wih_lds[idx] = W_ih[gr2 * 19 + kk];
    }
    const float bsum = b_ih[grow] + b_hh[grow];

    float pj[6];
    #pragma unroll
    for (int o = 0; o < 6; ++o) pj[o] = 0.f;
    if (wave == 1 && lane < 16) {
        #pragma unroll
        for (int o = 0; o < 3; ++o) {
            pj[o]     = W_a[o * 512 + (w << 4) + lane];
            pj[o + 3] = W_b[o * 512 + (w << 4) + lane];
        }
    }

    float c_reg = 0.0f;
    __syncthreads();

    float sav = (wave == 0 && lane < 19) ? sa[lane] : 0.f;

    for (int t = 0; t < T_STEPS; ++t) {
        // ---- 0. gx on the fly (independent of h) ----
        float gxv = bsum;
        if (wave == 0) {
            #pragma unroll
            for (int k = 0; k < 19; ++k)
                gxv = fmaf(__shfl(sav, k), wih_lds[r * 19 + k], gxv);
        }
        float sav_n = 0.f;
        if (wave == 0 && lane < 19 && t + 1 < T_STEPS)
            sav_n = sa[(size_t)(t + 1) * 19 + lane];

        // ---- 1. wait for h_{t-1}: single L2-RMW poll on the step counter ----
        if (t > 0) {
            if (tid == 0) {
                const uint32 need = 32u * (uint32)t;
                while (poll32(myctr) < need) {}
            }
            __syncthreads();
            // gather: plain loads (fresh via depth-D rotation); tag-verified
            ull* sp = hb + (size_t)((uint32)(t - 1) & dmask) * 512 + 2 * tid;
            const uint32 tag = (uint32)t;
            u32x4 v = *(const u32x4*)sp;
            if (v.x != tag || v.z != tag) {          // stale L1 line -> L2 RMW rescue
                ull a = rmw64(sp);
                while ((uint32)a != tag) a = rmw64(sp);
                ull b = rmw64(sp + 1);
                while ((uint32)b != tag) b = rmw64(sp + 1);
                v.x = (uint32)a; v.y = (uint32)(a >> 32);
                v.z = (uint32)b; v.w = (uint32)(b >> 32);
            }
            *(float2*)&h_lds[2 * tid] =
                make_float2(__uint_as_float(v.y), __uint_as_float(v.w));
        } else {
            *(float2*)&h_lds[2 * tid] = make_float2(0.f, 0.f);
        }
        __syncthreads();

        float hprev = 0.f;
        if (wave == 1 && lane < 16) hprev = h_lds[(w << 4) + lane];

        // ---- 2. mat-vec partial: row r, cols [wave*128, wave*128+128) ----
        {
            const float4* hp4 = (const float4*)(h_lds + wave * 128);
            float ax = 0.f, ay = 0.f, az = 0.f, aw = 0.f;
            #pragma unroll
            for (int k = 0; k < 32; ++k) {
                float4 wv = wreg[k];
                float4 hv = hp4[k];
                ax = fmaf(wv.x, hv.x, ax);
                ay = fmaf(wv.y, hv.y, ay);
                az = fmaf(wv.z, hv.z, az);
                aw = fmaf(wv.w, hv.w, aw);
            }
            part_lds[r * 5 + wave] = (ax + ay) + (az + aw);
        }
        __syncthreads();

        // ---- 3. gate assembly + cell update + publish (wave 0) ----
        if (wave == 0) {
            float pre = part_lds[r * 5] + part_lds[r * 5 + 1] +
                        part_lds[r * 5 + 2] + part_lds[r * 5 + 3] + gxv;

            const int g = r >> 4;
            float act = (g == 2) ? ftanh(pre) : fsig(pre);

            float i_v = __shfl(act, jloc);
            float f_v = __shfl(act, 16 + jloc);
            float g_v = __shfl(act, 32 + jloc);
            float o_v = __shfl(act, 48 + jloc);

            if (r < 16) {
                c_reg = f_v * c_reg + i_v * g_v;
                float hn = o_v * ftanh(c_reg);
                ull pk = ((ull)__float_as_uint(hn) << 32) | (ull)(uint32)(t + 1);
                // plain write-through store into the local XCD L2
                __hip_atomic_store(&hb[(size_t)((uint32)t & dmask) * 512 + (w << 4) + jloc],
                                   pk, __ATOMIC_RELAXED, __HIP_MEMORY_SCOPE_WORKGROUP);
            }
            // drain the wave's stores into L2, then bump the step counter (L2 RMW)
            asm volatile("s_waitcnt vmcnt(0)" ::: "memory");
            if (lane == 0)
                __hip_atomic_fetch_add(myctr, 1u, __ATOMIC_RELAXED,
                                       __HIP_MEMORY_SCOPE_WORKGROUP);
        }
        // ---- 4. deferred output projection for out[t-1] (wave 1) ----
        else if (wave == 1 && lane < 16 && t > 0) {
            #pragma unroll
            for (int o = 0; o < 6; ++o) {
                float v = hprev * pj[o];
                v += __shfl_xor(v, 1);
                v += __shfl_xor(v, 2);
                v += __shfl_xor(v, 4);
                v += __shfl_xor(v, 8);
                if (lane == 0) {
                    int col = (o < 3) ? (3 * lstm + o) : (6 + 3 * lstm + (o - 3));
                    atomicAdd(&out[(size_t)(t - 1) * 12 + col], v);
                }
            }
        }
        sav = sav_n;
    }

    // ---- final projection for out[T-1] (L2-RMW spin; always fresh) ----
    if (wave == 1 && lane < 16) {
        ull* src = hb + (size_t)((uint32)(T_STEPS - 1) & dmask) * 512 + (w << 4) + lane;
        ull v = rmw64(src);
        while ((uint32)v != (uint32)T_STEPS) v = rmw64(src);
        float hl = __uint_as_float((uint32)(v >> 32));
        #pragma unroll
        for (int o = 0; o < 6; ++o) {
            float s = hl * pj[o];
            s += __shfl_xor(s, 1);
            s += __shfl_xor(s, 2);
            s += __shfl_xor(s, 4);
            s += __shfl_xor(s, 8);
            if (lane == 0) {
                int col = (o < 3) ? (3 * lstm + o) : (6 + 3 * lstm + (o - 3));
                atomicAdd(&out[(size_t)(T_STEPS - 1) * 12 + col], s);
            }
        }
    }
}

__global__ void init_out(const float* __restrict__ b_xyz, const float* __restrict__ b_zeta,
                         const float* __restrict__ b_uvw, const float* __restrict__ b_pqr,
                         float* __restrict__ out)
{
    int idx = blockIdx.x * blockDim.x + threadIdx.x;
    if (idx < T_STEPS * 12) {
        int o = idx % 12;
        float v;
        if (o < 3)      v = b_xyz[o];
        else if (o < 6) v = b_zeta[o - 3];
        else if (o < 9) v = b_uvw[o - 6];
        else            v = b_pqr[o - 9];
        out[idx] = v;
    }
}

extern "C" void kernel_launch(void* const* d_in, const int* in_sizes, int n_in,
                              void* d_out, int out_size, void* d_ws, size_t ws_size,
                              hipStream_t stream)
{
    const float* sa    = (const float*)d_in[0];
    const float* W_ih1 = (const float*)d_in[1];
    const float* W_hh1 = (const float*)d_in[2];
    const float* b_ih1 = (const float*)d_in[3];
    const float* b_hh1 = (const float*)d_in[4];
    const float* W_ih2 = (const float*)d_in[5];
    const float* W_hh2 = (const float*)d_in[6];
    const float* b_ih2 = (const float*)d_in[7];
    const float* b_hh2 = (const float*)d_in[8];
    const float* W_xyz = (const float*)d_in[9];
    const float* b_xyz = (const float*)d_in[10];
    const float* W_zeta= (const float*)d_in[11];
    const float* b_zeta= (const float*)d_in[12];
    const float* W_uvw = (const float*)d_in[13];
    const float* b_uvw = (const float*)d_in[14];
    const float* W_pqr = (const float*)d_in[15];
    const float* b_pqr = (const float*)d_in[16];

    float* out = (float*)d_out;

    // pick rotation depth by available workspace (16 preferred: 64KB/LSTM
    // reuse distance guarantees L1 capacity eviction -> fresh plain loads)
    uint32 D = 16;
    while (D > 4 && ws_size < (size_t)2 * D * 4096 + 256) D >>= 1;
    size_t hbytes = (size_t)2 * D * 4096;

    ull*    hrot  = (ull*)d_ws;
    uint32* ctr   = (uint32*)((char*)d_ws + hbytes);
    uint32* claim = ctr + 32;   // 128B after ctr

    hipMemsetAsync(d_ws, 0, hbytes + 256, stream);
    init_out<<<(T_STEPS * 12 + 255) / 256, 256, 0, stream>>>(b_xyz, b_zeta, b_uvw, b_pqr, out);

    lstm_persistent<<<NLAUNCH, THREADS, 0, stream>>>(
        sa, W_ih1, W_hh1, b_ih1, b_hh1, W_ih2, W_hh2, b_ih2, b_hh2,
        W_xyz, W_zeta, W_uvw, W_pqr, out, hrot, ctr, claim, D - 1);
}